// Round 5
// baseline (877.317 us; speedup 1.0000x reference)
//
#include <hip/hip_runtime.h>
#include <hip/hip_bf16.h>
#include <math.h>

// CnnLstmCrf on MI355X, fp32-exact. Round 7: defeat rematerialization.
// Round-6 post-mortem: VGPR_Count=64 AGAIN. Mechanism: W loads are
// loop-invariant loads from __restrict__ readonly memory => LLVM considers
// them freely rematerializable, sinks them INTO the loop (re-executed every
// step) and keeps its preferred 64-reg/8-wave occupancy tier. launch_bounds
// is only a floor; remat looks free so pressure never forces more regs.
// Check: ~400thr x 400B reloaded/step = 160KB/block/step via L2 ~ 2900cy
// = measured 3650cy/step. Rounds 0-6 all share this reload => all ~310-380us.
// Fix: after loading the 25 named float4 weights, pass each component
// through asm volatile("" : "+v"(w)). In-out constraint makes the value
// opaque => remat illegal => 100 floats stay live in VGPRs (floor 256 regs
// via __launch_bounds__(448,2), pressure ~150 => no spill). Empty asm, no
// numeric change; expression text unchanged => bit-identical tags.
// LSTM decomposition (unchanged from round 6):
//  - 448 threads (7 waves), ONE gate row per lane: v=t>>2 (unit), s=t&3
//    (gate i/f/g/o), row=s*100+v => 25 float4 weight regs/thread.
//  - h broadcast: lane q (q<25) holds h chunk q via one ds_read_b128 per
//    wave; redistributed by v_readlane (VALU/SALU, no LDS pressure).
//  - gates of unit v live in lanes 4v..4v+3; three __shfl_xor hand f,g,o to
//    lane 4v (s==0) which runs the verbatim nonlin and writes h.
//  - h double-buffered in LDS; ONE unconditional __syncthreads() per step.
// Sizes: B=64 S=250 CL=16 CV=100 CD=300 CH=50 WD=300 FD=5
// IN=355 H=100 4H=400 HD=200 T=22 START=20 STOP=21
//
// Workspace layout (floats). lstm_out/feats alias the wrep region (dead after gemm).
#define WS_U        0          // 15000 -> pad 15360
#define WS_WPAD     15360      // 896*384 = 344064
#define WS_WREP     359424     // 16000*384 = 6144000 (reused below)
#define WS_PRE      6503424    // 16000*800 = 12800000 (end 19303424 floats = 77.2MB)
#define WS_LSTM     359424     // alias wrep: 16000*200 = 3200000 (< 6144000)
#define WS_FEATS    3559424    // alias wrep tail: 16000*22 = 352000 (ends 3911424)

// ---------------- prep: pad w_ih into [896][384] ----------------
__global__ __launch_bounds__(256) void prepw_kernel(
    const float* __restrict__ wf, const float* __restrict__ wb,
    float* __restrict__ w_pad) {
  int idx = blockIdx.x * 256 + threadIdx.x;
  if (idx >= 896 * 384) return;
  int col = idx % 384, row = idx / 384;
  float v = 0.f;
  if (col < 355) {
    if (row < 400)      v = wf[row * 355 + col];
    else if (row < 800) v = wb[(row - 400) * 355 + col];
  }
  w_pad[idx] = v;
}

// ---------------- U table: U[(c*3+k)*50+o] ----------------
__global__ __launch_bounds__(256) void u_kernel(
    const float* __restrict__ char_emb, const float* __restrict__ conv_w,
    float* __restrict__ U) {
  int idx = blockIdx.x * 256 + threadIdx.x;
  if (idx >= 15000) return;
  int c = idx / 150, rem = idx % 150, k = rem / 50, o = rem % 50;
  float acc = 0.f;
  for (int i = 0; i < 300; i++)
    acc += char_emb[c * 300 + i] * conv_w[(o * 300 + i) * 3 + k];
  U[idx] = acc;
}

// ---------------- assemble word_rep rows ----------------
__global__ __launch_bounds__(64) void assemble_kernel(
    const int* __restrict__ batch_word, const int* __restrict__ batch_feats,
    const int* __restrict__ batch_char, const int* __restrict__ recover,
    const float* __restrict__ word_emb, const float* __restrict__ feat_emb,
    const float* __restrict__ conv_b, const float* __restrict__ U,
    float* __restrict__ wrep) {
  int n = blockIdx.x;
  int tid = threadIdx.x;
  __shared__ int ch[16];
  if (tid < 16) ch[tid] = batch_char[(size_t)recover[n] * 16 + tid];
  __syncthreads();
  float* dst = wrep + (size_t)n * 384;
  int w = batch_word[n];
  for (int i = tid; i < 300; i += 64) dst[i] = word_emb[(size_t)w * 300 + i];
  if (tid < 34) {  // feat_emb (5) + zero pad (29)
    int i = 350 + tid;
    dst[i] = (i < 355) ? feat_emb[batch_feats[n] * 5 + (i - 350)] : 0.f;
  }
  if (tid < 50) {  // char CNN via U table, max over 16 positions
    int o = tid;
    float bo = conv_b[o];
    float m = -1e30f;
#pragma unroll
    for (int l = 0; l < 16; l++) {
      float v = bo + U[(ch[l] * 3 + 1) * 50 + o];
      if (l > 0)  v += U[(ch[l - 1] * 3 + 0) * 50 + o];
      if (l < 15) v += U[(ch[l + 1] * 3 + 2) * 50 + o];
      m = fmaxf(m, v);
    }
    dst[300 + o] = m;
  }
}

// ---------------- fp32 GEMM: C[16000][800] = A[16000][384] @ B[896][384]^T + bias
__global__ __launch_bounds__(256, 4) void gemm_kernel(
    const float* __restrict__ A, const float* __restrict__ B,
    float* __restrict__ C, const float* __restrict__ bf,
    const float* __restrict__ bb) {
  __shared__ float As[16][128];
  __shared__ float Bs[16][128];
  int tid = threadIdx.x;
  int m0 = blockIdx.x * 128;
  int n0 = blockIdx.y * 128;
  int tx = tid & 15, ty = tid >> 4;
  int lr = tid >> 2;
  int lc = (tid & 3) * 4;
  float acc[8][8];
#pragma unroll
  for (int i = 0; i < 8; i++)
#pragma unroll
    for (int j = 0; j < 8; j++) acc[i][j] = 0.f;

  for (int k0 = 0; k0 < 384; k0 += 16) {
#pragma unroll
    for (int h = 0; h < 2; h++) {
      int row = lr + h * 64;
      float4 av = *(const float4*)(A + (size_t)(m0 + row) * 384 + k0 + lc);
      As[lc + 0][row] = av.x; As[lc + 1][row] = av.y;
      As[lc + 2][row] = av.z; As[lc + 3][row] = av.w;
      float4 bv = *(const float4*)(B + (size_t)(n0 + row) * 384 + k0 + lc);
      Bs[lc + 0][row] = bv.x; Bs[lc + 1][row] = bv.y;
      Bs[lc + 2][row] = bv.z; Bs[lc + 3][row] = bv.w;
    }
    __syncthreads();
#pragma unroll
    for (int k = 0; k < 16; k++) {
      float a[8], b[8];
      *(float4*)&a[0] = *(const float4*)&As[k][ty * 8];
      *(float4*)&a[4] = *(const float4*)&As[k][ty * 8 + 4];
      *(float4*)&b[0] = *(const float4*)&Bs[k][tx * 8];
      *(float4*)&b[4] = *(const float4*)&Bs[k][tx * 8 + 4];
#pragma unroll
      for (int i = 0; i < 8; i++)
#pragma unroll
        for (int j = 0; j < 8; j++) acc[i][j] += a[i] * b[j];
    }
    __syncthreads();
  }
#pragma unroll
  for (int i = 0; i < 8; i++) {
    int m = m0 + ty * 8 + i;
#pragma unroll
    for (int jj = 0; jj < 8; jj++) {
      int j = n0 + tx * 8 + jj;
      if (j < 800) {
        float bias = (j < 400) ? bf[j] : bb[j - 400];
        C[(size_t)m * 800 + j] = acc[i][jj] + bias;
      }
    }
  }
}

// ---------------- BiLSTM scan: 128 blocks = (dir, row), 448 threads --------
__global__ __launch_bounds__(448, 2) void lstm_kernel(
    const float* __restrict__ pre, const float* __restrict__ w_hh_f,
    const float* __restrict__ w_hh_b, const int* __restrict__ wordlen,
    float* __restrict__ lstm_out) {
  int t = threadIdx.x;
  int lane = t & 63;
  int dir = blockIdx.x >> 6;
  int r = blockIdx.x & 63;
  int len = wordlen[r];
  const float* __restrict__ Wh = dir ? w_hh_b : w_hh_f;
  __shared__ __align__(16) float h0[112];
  __shared__ __align__(16) float h1[112];

  const int v = t >> 2;              // hidden unit
  const int s = t & 3;               // gate: 0=i, 1=f, 2=g, 3=o
  const bool act = (v < 100);
  const int row = act ? (s * 100 + v) : 0;  // clamp inactive lanes to row 0

  // 25 NAMED float4 weight regs
  const float4* wr = (const float4*)(Wh + (size_t)row * 100);
  float4 W00 = wr[0],  W01 = wr[1],  W02 = wr[2],  W03 = wr[3],  W04 = wr[4];
  float4 W05 = wr[5],  W06 = wr[6],  W07 = wr[7],  W08 = wr[8],  W09 = wr[9];
  float4 W10 = wr[10], W11 = wr[11], W12 = wr[12], W13 = wr[13], W14 = wr[14];
  float4 W15 = wr[15], W16 = wr[16], W17 = wr[17], W18 = wr[18], W19 = wr[19];
  float4 W20 = wr[20], W21 = wr[21], W22 = wr[22], W23 = wr[23], W24 = wr[24];

  // PIN: make each weight opaque so the allocator cannot rematerialize the
  // loads inside the loop (the round-5/6 failure mode). Empty asm => no
  // numeric effect; forces the 100 floats to stay live in VGPRs.
#define PIN4(W) asm volatile("" : "+v"(W.x), "+v"(W.y), "+v"(W.z), "+v"(W.w))
  PIN4(W00); PIN4(W01); PIN4(W02); PIN4(W03); PIN4(W04);
  PIN4(W05); PIN4(W06); PIN4(W07); PIN4(W08); PIN4(W09);
  PIN4(W10); PIN4(W11); PIN4(W12); PIN4(W13); PIN4(W14);
  PIN4(W15); PIN4(W16); PIN4(W17); PIN4(W18); PIN4(W19);
  PIN4(W20); PIN4(W21); PIN4(W22); PIN4(W23); PIN4(W24);
#undef PIN4

  if (t < 112) { h0[t] = 0.f; h1[t] = 0.f; }

  float c_reg = 0.f, h_reg = 0.f;
  const float* __restrict__ pr = pre + dir * 400;
  const int p0 = dir ? 249 : 0;
  const int dp = dir ? -1 : 1;
  const size_t rowbase = (size_t)r * 250;

  // depth-2 prefetch of this lane's pre column (steps 0 and 1)
  float pvA = 0.f, pvB = 0.f;
  if (act) {
    pvA = pr[(rowbase + (size_t)p0) * 800 + row];
    pvB = pr[(rowbase + (size_t)(p0 + dp)) * 800 + row];
  }
  const int cl = (lane < 25) ? lane : 0;  // h chunk owned by this lane
  __syncthreads();  // h buffers + weights ready

#define RL(x, q) __uint_as_float(__builtin_amdgcn_readlane(__float_as_uint(x), (q)))
#define DOTQ(q, Wq)                                                            \
  g += RL(hch.x, q) * Wq.x + RL(hch.y, q) * Wq.y + RL(hch.z, q) * Wq.z +       \
       RL(hch.w, q) * Wq.w;

#define LSTM_STEP(I, HRD, HWR, PV)                                             \
  do {                                                                         \
    const int p = p0 + dp * (I);                                               \
    const bool valid = (p < len); /* block-uniform */                          \
    float g = 0.f;                                                             \
    if (valid) {                                                               \
      float4 hch = *(const float4*)&(HRD)[4 * cl];                             \
      g = PV;                                                                  \
      DOTQ(0, W00)  DOTQ(1, W01)  DOTQ(2, W02)  DOTQ(3, W03)  DOTQ(4, W04)    \
      DOTQ(5, W05)  DOTQ(6, W06)  DOTQ(7, W07)  DOTQ(8, W08)  DOTQ(9, W09)    \
      DOTQ(10, W10) DOTQ(11, W11) DOTQ(12, W12) DOTQ(13, W13) DOTQ(14, W14)   \
      DOTQ(15, W15) DOTQ(16, W16) DOTQ(17, W17) DOTQ(18, W18) DOTQ(19, W19)   \
      DOTQ(20, W20) DOTQ(21, W21) DOTQ(22, W22) DOTQ(23, W23) DOTQ(24, W24)   \
    }                                                                          \
    if (act) { /* keep prefetch pipeline running every step */                 \
      const int ip = ((I) + 2 < 250) ? (I) + 2 : (I);                          \
      PV = pr[(rowbase + (size_t)(p0 + dp * ip)) * 800 + row];                 \
    }                                                                          \
    if (valid) {                                                               \
      const float gf_in = __shfl_xor(g, 1, 64); /* lane 4v gets f-gate */      \
      const float gg_in = __shfl_xor(g, 2, 64); /* lane 4v gets g-gate */      \
      const float go_in = __shfl_xor(g, 3, 64); /* lane 4v gets o-gate */      \
      if (act && s == 0) {                                                     \
        const float si = 1.f / (1.f + expf(-g));                               \
        const float sf = 1.f / (1.f + expf(-gf_in));                           \
        const float so = 1.f / (1.f + expf(-go_in));                           \
        c_reg = sf * c_reg + si * tanhf(gg_in);                                \
        h_reg = so * tanhf(c_reg);                                             \
        (HWR)[v] = h_reg;                                                      \
        lstm_out[(rowbase + (size_t)p) * 200 + dir * 100 + v] = h_reg;         \
      }                                                                        \
    } else if (act && s == 0) {                                                \
      /* masked step: carry h (h_sh untouched => no race with skipped dot) */  \
      lstm_out[(rowbase + (size_t)p) * 200 + dir * 100 + v] = h_reg;           \
    }                                                                          \
    __syncthreads(); /* ONE unconditional barrier per step */                  \
  } while (0)

#pragma unroll 1
  for (int ii = 0; ii < 250; ii += 2) {
    LSTM_STEP(ii,     h0, h1, pvA);
    LSTM_STEP(ii + 1, h1, h0, pvB);
  }
#undef LSTM_STEP
#undef DOTQ
#undef RL
}

// ---------------- projection: feats = lstm_out @ proj_w + proj_b ----------------
__global__ __launch_bounds__(256) void proj_kernel(
    const float* __restrict__ lstm_out, const float* __restrict__ proj_w,
    const float* __restrict__ proj_b, float* __restrict__ feats) {
  __shared__ float L[8][200];
  int tid = threadIdx.x;
  size_t base = (size_t)blockIdx.x * 8 * 200;
  for (int idx = tid; idx < 1600; idx += 256)
    L[idx / 200][idx % 200] = lstm_out[base + idx];
  __syncthreads();
  int ty = tid >> 5, c = tid & 31;
  if (c < 22) {
    float acc = proj_b[c];
#pragma unroll 8
    for (int k = 0; k < 200; k++) acc += L[ty][k] * proj_w[k * 22 + c];
    feats[((size_t)blockIdx.x * 8 + ty) * 22 + c] = acc;
  }
}

// ---------------- Viterbi: one wave per batch row (BORING: LDS delta) ----------
__global__ __launch_bounds__(64) void viterbi_kernel(
    const float* __restrict__ feats, const float* __restrict__ trans,
    const int* __restrict__ wordlen, int* __restrict__ out) {
  int r = blockIdx.x;
  int lane = threadIdx.x;
  __shared__ float dsh[22];          // delta (current)
  __shared__ float tsh[22][23];      // trans[k][c], padded stride 23
  __shared__ unsigned char bps[250][22];
  int len = wordlen[r];
  const float* __restrict__ fr = feats + (size_t)r * 250 * 22;
  for (int idx = lane; idx < 484; idx += 64)
    tsh[idx / 22][idx % 22] = trans[idx];
  if (lane < 22) dsh[lane] = trans[20 * 22 + lane] + fr[lane];  // START row
  __syncthreads();
  for (int t = 1; t < 250; t++) {
    float best = -1e30f, fv = 0.f;
    int arg = 0;
    if (lane < 22) {
      fv = fr[t * 22 + lane];
#pragma unroll
      for (int k = 0; k < 22; k++) {
        float cand = dsh[k] + tsh[k][lane];
        if (cand > best) { best = cand; arg = k; }  // first-max == np.argmax
      }
    }
    __syncthreads();  // all dsh reads complete
    if (lane < 22) {
      bool valid = t < len;
      if (valid) dsh[lane] = best + fv;
      bps[t][lane] = valid ? (unsigned char)arg : (unsigned char)lane;
    }
    __syncthreads();  // dsh writes visible
  }
  if (lane == 0) {
    float best = -1e30f;
    int last = 0;
#pragma unroll
    for (int k = 0; k < 22; k++) {
      float cand = dsh[k] + tsh[k][21];  // + trans[:, STOP]
      if (cand > best) { best = cand; last = k; }
    }
    int tag = last;
    out[r * 250 + 249] = tag;
    for (int t = 249; t >= 1; t--) {
      tag = bps[t][tag];
      out[r * 250 + t - 1] = tag;
    }
  }
}

extern "C" void kernel_launch(void* const* d_in, const int* in_sizes, int n_in,
                              void* d_out, int out_size, void* d_ws, size_t ws_size,
                              hipStream_t stream) {
  const int* batch_word  = (const int*)d_in[0];
  const int* batch_feats = (const int*)d_in[1];
  const int* wordlen     = (const int*)d_in[2];
  const int* batch_char  = (const int*)d_in[3];
  // d_in[4] batch_charlen: unused by reference
  const int* recover     = (const int*)d_in[5];
  // d_in[6] mask: recomputed from wordlen (bool dtype ambiguity)
  const float* char_emb  = (const float*)d_in[7];
  const float* word_emb  = (const float*)d_in[8];
  const float* feat_emb  = (const float*)d_in[9];
  const float* conv_w    = (const float*)d_in[10];
  const float* conv_b    = (const float*)d_in[11];
  const float* w_ih_f    = (const float*)d_in[12];
  const float* w_hh_f    = (const float*)d_in[13];
  const float* b_f       = (const float*)d_in[14];
  const float* w_ih_b    = (const float*)d_in[15];
  const float* w_hh_b    = (const float*)d_in[16];
  const float* b_b       = (const float*)d_in[17];
  const float* proj_w    = (const float*)d_in[18];
  const float* proj_b    = (const float*)d_in[19];
  const float* trans     = (const float*)d_in[20];
  int* out = (int*)d_out;
  float* ws = (float*)d_ws;

  float* U        = ws + WS_U;
  float* w_pad    = ws + WS_WPAD;
  float* wrep     = ws + WS_WREP;
  float* pre      = ws + WS_PRE;
  float* lstm_out = ws + WS_LSTM;   // aliases wrep (dead after gemm)
  float* feats    = ws + WS_FEATS;  // aliases wrep tail

  prepw_kernel<<<1344, 256, 0, stream>>>(w_ih_f, w_ih_b, w_pad);
  u_kernel<<<59, 256, 0, stream>>>(char_emb, conv_w, U);
  assemble_kernel<<<16000, 64, 0, stream>>>(batch_word, batch_feats, batch_char,
                                            recover, word_emb, feat_emb, conv_b,
                                            U, wrep);
  dim3 ggrid(125, 7);
  gemm_kernel<<<ggrid, 256, 0, stream>>>(wrep, w_pad, pre, b_f, b_b);
  lstm_kernel<<<128, 448, 0, stream>>>(pre, w_hh_f, w_hh_b, wordlen, lstm_out);
  proj_kernel<<<2000, 256, 0, stream>>>(lstm_out, proj_w, proj_b, feats);
  viterbi_kernel<<<64, 64, 0, stream>>>(feats, trans, wordlen, out);
}

// Round 6
// 857.909 us; speedup vs baseline: 1.0226x; 1.0226x over previous
//
#include <hip/hip_runtime.h>
#include <hip/hip_bf16.h>
#include <math.h>

// CnnLstmCrf on MI355X, fp32-exact. Round 8: set the occupancy TARGET, not
// just the floor. Rounds 5-7 post-mortem: VGPR_Count=64 every time. The
// AMDGPU backend picks a target occupancy BEFORE regalloc; launch_bounds'
// 2nd arg only sets the MIN waves/EU (reg cap), while the scheduler still
// targets the default 8 waves/EU = 64-reg tier, then remats (r5/r6) or
// spills (r7: pins -> scratch, SGPR 48->112, dur 380->402) to hit it.
// Physical truth: 128 blocks / 256 CUs = 1 block/CU, 7 waves = ~2 waves/EU.
// Fix: __attribute__((amdgpu_waves_per_eu(2,2))) tells the compiler the max
// achievable occupancy IS 2 waves/EU -> 256-reg budget usable -> ~150 regs
// of pressure (100 weight floats + state) allocates with NO spill/remat.
// Pins kept (belt+suspenders vs remat). Everything else byte-identical.
// Verification gate (pre-committed): VGPR_Count >= 150, dur ~100-150us.
// LSTM decomposition (unchanged since round 5):
//  - 448 threads (7 waves), ONE gate row per lane: v=t>>2 (unit), s=t&3
//    (gate i/f/g/o), row=s*100+v => 25 float4 weight regs/thread.
//  - h broadcast: lane q (q<25) holds h chunk q via one ds_read_b128 per
//    wave; redistributed by v_readlane (VALU, no LDS pressure).
//  - gates of unit v live in lanes 4v..4v+3; three __shfl_xor hand f,g,o to
//    lane 4v (s==0) which runs the verbatim nonlin and writes h.
//  - h double-buffered in LDS; ONE unconditional __syncthreads() per step.
// Sizes: B=64 S=250 CL=16 CV=100 CD=300 CH=50 WD=300 FD=5
// IN=355 H=100 4H=400 HD=200 T=22 START=20 STOP=21
//
// Workspace layout (floats). lstm_out/feats alias the wrep region (dead after gemm).
#define WS_U        0          // 15000 -> pad 15360
#define WS_WPAD     15360      // 896*384 = 344064
#define WS_WREP     359424     // 16000*384 = 6144000 (reused below)
#define WS_PRE      6503424    // 16000*800 = 12800000 (end 19303424 floats = 77.2MB)
#define WS_LSTM     359424     // alias wrep: 16000*200 = 3200000 (< 6144000)
#define WS_FEATS    3559424    // alias wrep tail: 16000*22 = 352000 (ends 3911424)

// ---------------- prep: pad w_ih into [896][384] ----------------
__global__ __launch_bounds__(256) void prepw_kernel(
    const float* __restrict__ wf, const float* __restrict__ wb,
    float* __restrict__ w_pad) {
  int idx = blockIdx.x * 256 + threadIdx.x;
  if (idx >= 896 * 384) return;
  int col = idx % 384, row = idx / 384;
  float v = 0.f;
  if (col < 355) {
    if (row < 400)      v = wf[row * 355 + col];
    else if (row < 800) v = wb[(row - 400) * 355 + col];
  }
  w_pad[idx] = v;
}

// ---------------- U table: U[(c*3+k)*50+o] ----------------
__global__ __launch_bounds__(256) void u_kernel(
    const float* __restrict__ char_emb, const float* __restrict__ conv_w,
    float* __restrict__ U) {
  int idx = blockIdx.x * 256 + threadIdx.x;
  if (idx >= 15000) return;
  int c = idx / 150, rem = idx % 150, k = rem / 50, o = rem % 50;
  float acc = 0.f;
  for (int i = 0; i < 300; i++)
    acc += char_emb[c * 300 + i] * conv_w[(o * 300 + i) * 3 + k];
  U[idx] = acc;
}

// ---------------- assemble word_rep rows ----------------
__global__ __launch_bounds__(64) void assemble_kernel(
    const int* __restrict__ batch_word, const int* __restrict__ batch_feats,
    const int* __restrict__ batch_char, const int* __restrict__ recover,
    const float* __restrict__ word_emb, const float* __restrict__ feat_emb,
    const float* __restrict__ conv_b, const float* __restrict__ U,
    float* __restrict__ wrep) {
  int n = blockIdx.x;
  int tid = threadIdx.x;
  __shared__ int ch[16];
  if (tid < 16) ch[tid] = batch_char[(size_t)recover[n] * 16 + tid];
  __syncthreads();
  float* dst = wrep + (size_t)n * 384;
  int w = batch_word[n];
  for (int i = tid; i < 300; i += 64) dst[i] = word_emb[(size_t)w * 300 + i];
  if (tid < 34) {  // feat_emb (5) + zero pad (29)
    int i = 350 + tid;
    dst[i] = (i < 355) ? feat_emb[batch_feats[n] * 5 + (i - 350)] : 0.f;
  }
  if (tid < 50) {  // char CNN via U table, max over 16 positions
    int o = tid;
    float bo = conv_b[o];
    float m = -1e30f;
#pragma unroll
    for (int l = 0; l < 16; l++) {
      float v = bo + U[(ch[l] * 3 + 1) * 50 + o];
      if (l > 0)  v += U[(ch[l - 1] * 3 + 0) * 50 + o];
      if (l < 15) v += U[(ch[l + 1] * 3 + 2) * 50 + o];
      m = fmaxf(m, v);
    }
    dst[300 + o] = m;
  }
}

// ---------------- fp32 GEMM: C[16000][800] = A[16000][384] @ B[896][384]^T + bias
__global__ __launch_bounds__(256, 4) void gemm_kernel(
    const float* __restrict__ A, const float* __restrict__ B,
    float* __restrict__ C, const float* __restrict__ bf,
    const float* __restrict__ bb) {
  __shared__ float As[16][128];
  __shared__ float Bs[16][128];
  int tid = threadIdx.x;
  int m0 = blockIdx.x * 128;
  int n0 = blockIdx.y * 128;
  int tx = tid & 15, ty = tid >> 4;
  int lr = tid >> 2;
  int lc = (tid & 3) * 4;
  float acc[8][8];
#pragma unroll
  for (int i = 0; i < 8; i++)
#pragma unroll
    for (int j = 0; j < 8; j++) acc[i][j] = 0.f;

  for (int k0 = 0; k0 < 384; k0 += 16) {
#pragma unroll
    for (int h = 0; h < 2; h++) {
      int row = lr + h * 64;
      float4 av = *(const float4*)(A + (size_t)(m0 + row) * 384 + k0 + lc);
      As[lc + 0][row] = av.x; As[lc + 1][row] = av.y;
      As[lc + 2][row] = av.z; As[lc + 3][row] = av.w;
      float4 bv = *(const float4*)(B + (size_t)(n0 + row) * 384 + k0 + lc);
      Bs[lc + 0][row] = bv.x; Bs[lc + 1][row] = bv.y;
      Bs[lc + 2][row] = bv.z; Bs[lc + 3][row] = bv.w;
    }
    __syncthreads();
#pragma unroll
    for (int k = 0; k < 16; k++) {
      float a[8], b[8];
      *(float4*)&a[0] = *(const float4*)&As[k][ty * 8];
      *(float4*)&a[4] = *(const float4*)&As[k][ty * 8 + 4];
      *(float4*)&b[0] = *(const float4*)&Bs[k][tx * 8];
      *(float4*)&b[4] = *(const float4*)&Bs[k][tx * 8 + 4];
#pragma unroll
      for (int i = 0; i < 8; i++)
#pragma unroll
        for (int j = 0; j < 8; j++) acc[i][j] += a[i] * b[j];
    }
    __syncthreads();
  }
#pragma unroll
  for (int i = 0; i < 8; i++) {
    int m = m0 + ty * 8 + i;
#pragma unroll
    for (int jj = 0; jj < 8; jj++) {
      int j = n0 + tx * 8 + jj;
      if (j < 800) {
        float bias = (j < 400) ? bf[j] : bb[j - 400];
        C[(size_t)m * 800 + j] = acc[i][jj] + bias;
      }
    }
  }
}

// ---------------- BiLSTM scan: 128 blocks = (dir, row), 448 threads --------
__global__ __attribute__((amdgpu_waves_per_eu(2, 2)))
__launch_bounds__(448) void lstm_kernel(
    const float* __restrict__ pre, const float* __restrict__ w_hh_f,
    const float* __restrict__ w_hh_b, const int* __restrict__ wordlen,
    float* __restrict__ lstm_out) {
  int t = threadIdx.x;
  int lane = t & 63;
  int dir = blockIdx.x >> 6;
  int r = blockIdx.x & 63;
  int len = wordlen[r];
  const float* __restrict__ Wh = dir ? w_hh_b : w_hh_f;
  __shared__ __align__(16) float h0[112];
  __shared__ __align__(16) float h1[112];

  const int v = t >> 2;              // hidden unit
  const int s = t & 3;               // gate: 0=i, 1=f, 2=g, 3=o
  const bool act = (v < 100);
  const int row = act ? (s * 100 + v) : 0;  // clamp inactive lanes to row 0

  // 25 NAMED float4 weight regs
  const float4* wr = (const float4*)(Wh + (size_t)row * 100);
  float4 W00 = wr[0],  W01 = wr[1],  W02 = wr[2],  W03 = wr[3],  W04 = wr[4];
  float4 W05 = wr[5],  W06 = wr[6],  W07 = wr[7],  W08 = wr[8],  W09 = wr[9];
  float4 W10 = wr[10], W11 = wr[11], W12 = wr[12], W13 = wr[13], W14 = wr[14];
  float4 W15 = wr[15], W16 = wr[16], W17 = wr[17], W18 = wr[18], W19 = wr[19];
  float4 W20 = wr[20], W21 = wr[21], W22 = wr[22], W23 = wr[23], W24 = wr[24];

  // PIN: keep each weight opaque (no remat). With waves_per_eu(2,2) the
  // allocator budget is 256 regs, so these stay resident (no spill either).
#define PIN4(W) asm volatile("" : "+v"(W.x), "+v"(W.y), "+v"(W.z), "+v"(W.w))
  PIN4(W00); PIN4(W01); PIN4(W02); PIN4(W03); PIN4(W04);
  PIN4(W05); PIN4(W06); PIN4(W07); PIN4(W08); PIN4(W09);
  PIN4(W10); PIN4(W11); PIN4(W12); PIN4(W13); PIN4(W14);
  PIN4(W15); PIN4(W16); PIN4(W17); PIN4(W18); PIN4(W19);
  PIN4(W20); PIN4(W21); PIN4(W22); PIN4(W23); PIN4(W24);
#undef PIN4

  if (t < 112) { h0[t] = 0.f; h1[t] = 0.f; }

  float c_reg = 0.f, h_reg = 0.f;
  const float* __restrict__ pr = pre + dir * 400;
  const int p0 = dir ? 249 : 0;
  const int dp = dir ? -1 : 1;
  const size_t rowbase = (size_t)r * 250;

  // depth-2 prefetch of this lane's pre column (steps 0 and 1)
  float pvA = 0.f, pvB = 0.f;
  if (act) {
    pvA = pr[(rowbase + (size_t)p0) * 800 + row];
    pvB = pr[(rowbase + (size_t)(p0 + dp)) * 800 + row];
  }
  const int cl = (lane < 25) ? lane : 0;  // h chunk owned by this lane
  __syncthreads();  // h buffers + weights ready

#define RL(x, q) __uint_as_float(__builtin_amdgcn_readlane(__float_as_uint(x), (q)))
#define DOTQ(q, Wq)                                                            \
  g += RL(hch.x, q) * Wq.x + RL(hch.y, q) * Wq.y + RL(hch.z, q) * Wq.z +       \
       RL(hch.w, q) * Wq.w;

#define LSTM_STEP(I, HRD, HWR, PV)                                             \
  do {                                                                         \
    const int p = p0 + dp * (I);                                               \
    const bool valid = (p < len); /* block-uniform */                          \
    float g = 0.f;                                                             \
    if (valid) {                                                               \
      float4 hch = *(const float4*)&(HRD)[4 * cl];                             \
      g = PV;                                                                  \
      DOTQ(0, W00)  DOTQ(1, W01)  DOTQ(2, W02)  DOTQ(3, W03)  DOTQ(4, W04)    \
      DOTQ(5, W05)  DOTQ(6, W06)  DOTQ(7, W07)  DOTQ(8, W08)  DOTQ(9, W09)    \
      DOTQ(10, W10) DOTQ(11, W11) DOTQ(12, W12) DOTQ(13, W13) DOTQ(14, W14)   \
      DOTQ(15, W15) DOTQ(16, W16) DOTQ(17, W17) DOTQ(18, W18) DOTQ(19, W19)   \
      DOTQ(20, W20) DOTQ(21, W21) DOTQ(22, W22) DOTQ(23, W23) DOTQ(24, W24)   \
    }                                                                          \
    if (act) { /* keep prefetch pipeline running every step */                 \
      const int ip = ((I) + 2 < 250) ? (I) + 2 : (I);                          \
      PV = pr[(rowbase + (size_t)(p0 + dp * ip)) * 800 + row];                 \
    }                                                                          \
    if (valid) {                                                               \
      const float gf_in = __shfl_xor(g, 1, 64); /* lane 4v gets f-gate */      \
      const float gg_in = __shfl_xor(g, 2, 64); /* lane 4v gets g-gate */      \
      const float go_in = __shfl_xor(g, 3, 64); /* lane 4v gets o-gate */      \
      if (act && s == 0) {                                                     \
        const float si = 1.f / (1.f + expf(-g));                               \
        const float sf = 1.f / (1.f + expf(-gf_in));                           \
        const float so = 1.f / (1.f + expf(-go_in));                           \
        c_reg = sf * c_reg + si * tanhf(gg_in);                                \
        h_reg = so * tanhf(c_reg);                                             \
        (HWR)[v] = h_reg;                                                      \
        lstm_out[(rowbase + (size_t)p) * 200 + dir * 100 + v] = h_reg;         \
      }                                                                        \
    } else if (act && s == 0) {                                                \
      /* masked step: carry h (h_sh untouched => no race with skipped dot) */  \
      lstm_out[(rowbase + (size_t)p) * 200 + dir * 100 + v] = h_reg;           \
    }                                                                          \
    __syncthreads(); /* ONE unconditional barrier per step */                  \
  } while (0)

#pragma unroll 1
  for (int ii = 0; ii < 250; ii += 2) {
    LSTM_STEP(ii,     h0, h1, pvA);
    LSTM_STEP(ii + 1, h1, h0, pvB);
  }
#undef LSTM_STEP
#undef DOTQ
#undef RL
}

// ---------------- projection: feats = lstm_out @ proj_w + proj_b ----------------
__global__ __launch_bounds__(256) void proj_kernel(
    const float* __restrict__ lstm_out, const float* __restrict__ proj_w,
    const float* __restrict__ proj_b, float* __restrict__ feats) {
  __shared__ float L[8][200];
  int tid = threadIdx.x;
  size_t base = (size_t)blockIdx.x * 8 * 200;
  for (int idx = tid; idx < 1600; idx += 256)
    L[idx / 200][idx % 200] = lstm_out[base + idx];
  __syncthreads();
  int ty = tid >> 5, c = tid & 31;
  if (c < 22) {
    float acc = proj_b[c];
#pragma unroll 8
    for (int k = 0; k < 200; k++) acc += L[ty][k] * proj_w[k * 22 + c];
    feats[((size_t)blockIdx.x * 8 + ty) * 22 + c] = acc;
  }
}

// ---------------- Viterbi: one wave per batch row (BORING: LDS delta) ----------
__global__ __launch_bounds__(64) void viterbi_kernel(
    const float* __restrict__ feats, const float* __restrict__ trans,
    const int* __restrict__ wordlen, int* __restrict__ out) {
  int r = blockIdx.x;
  int lane = threadIdx.x;
  __shared__ float dsh[22];          // delta (current)
  __shared__ float tsh[22][23];      // trans[k][c], padded stride 23
  __shared__ unsigned char bps[250][22];
  int len = wordlen[r];
  const float* __restrict__ fr = feats + (size_t)r * 250 * 22;
  for (int idx = lane; idx < 484; idx += 64)
    tsh[idx / 22][idx % 22] = trans[idx];
  if (lane < 22) dsh[lane] = trans[20 * 22 + lane] + fr[lane];  // START row
  __syncthreads();
  for (int t = 1; t < 250; t++) {
    float best = -1e30f, fv = 0.f;
    int arg = 0;
    if (lane < 22) {
      fv = fr[t * 22 + lane];
#pragma unroll
      for (int k = 0; k < 22; k++) {
        float cand = dsh[k] + tsh[k][lane];
        if (cand > best) { best = cand; arg = k; }  // first-max == np.argmax
      }
    }
    __syncthreads();  // all dsh reads complete
    if (lane < 22) {
      bool valid = t < len;
      if (valid) dsh[lane] = best + fv;
      bps[t][lane] = valid ? (unsigned char)arg : (unsigned char)lane;
    }
    __syncthreads();  // dsh writes visible
  }
  if (lane == 0) {
    float best = -1e30f;
    int last = 0;
#pragma unroll
    for (int k = 0; k < 22; k++) {
      float cand = dsh[k] + tsh[k][21];  // + trans[:, STOP]
      if (cand > best) { best = cand; last = k; }
    }
    int tag = last;
    out[r * 250 + 249] = tag;
    for (int t = 249; t >= 1; t--) {
      tag = bps[t][tag];
      out[r * 250 + t - 1] = tag;
    }
  }
}

extern "C" void kernel_launch(void* const* d_in, const int* in_sizes, int n_in,
                              void* d_out, int out_size, void* d_ws, size_t ws_size,
                              hipStream_t stream) {
  const int* batch_word  = (const int*)d_in[0];
  const int* batch_feats = (const int*)d_in[1];
  const int* wordlen     = (const int*)d_in[2];
  const int* batch_char  = (const int*)d_in[3];
  // d_in[4] batch_charlen: unused by reference
  const int* recover     = (const int*)d_in[5];
  // d_in[6] mask: recomputed from wordlen (bool dtype ambiguity)
  const float* char_emb  = (const float*)d_in[7];
  const float* word_emb  = (const float*)d_in[8];
  const float* feat_emb  = (const float*)d_in[9];
  const float* conv_w    = (const float*)d_in[10];
  const float* conv_b    = (const float*)d_in[11];
  const float* w_ih_f    = (const float*)d_in[12];
  const float* w_hh_f    = (const float*)d_in[13];
  const float* b_f       = (const float*)d_in[14];
  const float* w_ih_b    = (const float*)d_in[15];
  const float* w_hh_b    = (const float*)d_in[16];
  const float* b_b       = (const float*)d_in[17];
  const float* proj_w    = (const float*)d_in[18];
  const float* proj_b    = (const float*)d_in[19];
  const float* trans     = (const float*)d_in[20];
  int* out = (int*)d_out;
  float* ws = (float*)d_ws;

  float* U        = ws + WS_U;
  float* w_pad    = ws + WS_WPAD;
  float* wrep     = ws + WS_WREP;
  float* pre      = ws + WS_PRE;
  float* lstm_out = ws + WS_LSTM;   // aliases wrep (dead after gemm)
  float* feats    = ws + WS_FEATS;  // aliases wrep tail

  prepw_kernel<<<1344, 256, 0, stream>>>(w_ih_f, w_ih_b, w_pad);
  u_kernel<<<59, 256, 0, stream>>>(char_emb, conv_w, U);
  assemble_kernel<<<16000, 64, 0, stream>>>(batch_word, batch_feats, batch_char,
                                            recover, word_emb, feat_emb, conv_b,
                                            U, wrep);
  dim3 ggrid(125, 7);
  gemm_kernel<<<ggrid, 256, 0, stream>>>(wrep, w_pad, pre, b_f, b_b);
  lstm_kernel<<<128, 448, 0, stream>>>(pre, w_hh_f, w_hh_b, wordlen, lstm_out);
  proj_kernel<<<2000, 256, 0, stream>>>(lstm_out, proj_w, proj_b, feats);
  viterbi_kernel<<<64, 64, 0, stream>>>(feats, trans, wordlen, out);
}

// Round 7
// 839.428 us; speedup vs baseline: 1.0451x; 1.0220x over previous
//
#include <hip/hip_runtime.h>
#include <hip/hip_bf16.h>
#include <math.h>

// CnnLstmCrf on MI355X. Round 9: fit under the allocator instead of fighting
// it. Evidence (r5-r8): allocator grants at most ~88 VGPRs for this kernel
// (attr moved 64->88, no further); 100-float/thread weight arrays therefore
// ALWAYS spill/remat => 160KB/block/step scratch-or-L2 reloads = the stable
// ~370us. Fix: wave-level K-split so each thread holds HALF a row:
//  - 896 threads = 14 waves. Waves 0-6 ("group 0"): weight chunks q=0..12
//    (k=0..51) and the pre[] seed. Waves 7-13 ("group 1"): q=13..24
//    (k=52..99). Group is WAVE-uniform so readlane indices stay uniform.
//  - Per-thread: 13 float4 = 52 weight floats -> pressure ~78 < 88 grant.
//  - Within a group, thread u=(w%7)*64+lane owns row s*100+v (v=u>>2,s=u&3)
//    exactly as rounds 5-8.
//  - h broadcast: lanes 0-24 of each wave hold h chunks via one
//    ds_read_b128; readlane redistribution (VALU).
//  - Combine: group1 writes partial to g_sh[400] (LDS), barrier, group0
//    adds, shuffles gates to lane 4v (s==0), verbatim nonlin, writes h.
//    Two __syncthreads per step (plain, boring, r4-ghost-safe).
//  - Numerics: ONE reassociation point ((pv+lo)+(hi)); output is integer
//    Viterbi tags over continuous random data => tag-stable.
// Sizes: B=64 S=250 CL=16 CV=100 CD=300 CH=50 WD=300 FD=5
// IN=355 H=100 4H=400 HD=200 T=22 START=20 STOP=21
//
// Workspace layout (floats). lstm_out/feats alias the wrep region (dead after gemm).
#define WS_U        0          // 15000 -> pad 15360
#define WS_WPAD     15360      // 896*384 = 344064
#define WS_WREP     359424     // 16000*384 = 6144000 (reused below)
#define WS_PRE      6503424    // 16000*800 = 12800000 (end 19303424 floats = 77.2MB)
#define WS_LSTM     359424     // alias wrep: 16000*200 = 3200000 (< 6144000)
#define WS_FEATS    3559424    // alias wrep tail: 16000*22 = 352000 (ends 3911424)

// ---------------- prep: pad w_ih into [896][384] ----------------
__global__ __launch_bounds__(256) void prepw_kernel(
    const float* __restrict__ wf, const float* __restrict__ wb,
    float* __restrict__ w_pad) {
  int idx = blockIdx.x * 256 + threadIdx.x;
  if (idx >= 896 * 384) return;
  int col = idx % 384, row = idx / 384;
  float v = 0.f;
  if (col < 355) {
    if (row < 400)      v = wf[row * 355 + col];
    else if (row < 800) v = wb[(row - 400) * 355 + col];
  }
  w_pad[idx] = v;
}

// ---------------- U table: U[(c*3+k)*50+o] ----------------
__global__ __launch_bounds__(256) void u_kernel(
    const float* __restrict__ char_emb, const float* __restrict__ conv_w,
    float* __restrict__ U) {
  int idx = blockIdx.x * 256 + threadIdx.x;
  if (idx >= 15000) return;
  int c = idx / 150, rem = idx % 150, k = rem / 50, o = rem % 50;
  float acc = 0.f;
  for (int i = 0; i < 300; i++)
    acc += char_emb[c * 300 + i] * conv_w[(o * 300 + i) * 3 + k];
  U[idx] = acc;
}

// ---------------- assemble word_rep rows ----------------
__global__ __launch_bounds__(64) void assemble_kernel(
    const int* __restrict__ batch_word, const int* __restrict__ batch_feats,
    const int* __restrict__ batch_char, const int* __restrict__ recover,
    const float* __restrict__ word_emb, const float* __restrict__ feat_emb,
    const float* __restrict__ conv_b, const float* __restrict__ U,
    float* __restrict__ wrep) {
  int n = blockIdx.x;
  int tid = threadIdx.x;
  __shared__ int ch[16];
  if (tid < 16) ch[tid] = batch_char[(size_t)recover[n] * 16 + tid];
  __syncthreads();
  float* dst = wrep + (size_t)n * 384;
  int w = batch_word[n];
  for (int i = tid; i < 300; i += 64) dst[i] = word_emb[(size_t)w * 300 + i];
  if (tid < 34) {  // feat_emb (5) + zero pad (29)
    int i = 350 + tid;
    dst[i] = (i < 355) ? feat_emb[batch_feats[n] * 5 + (i - 350)] : 0.f;
  }
  if (tid < 50) {  // char CNN via U table, max over 16 positions
    int o = tid;
    float bo = conv_b[o];
    float m = -1e30f;
#pragma unroll
    for (int l = 0; l < 16; l++) {
      float v = bo + U[(ch[l] * 3 + 1) * 50 + o];
      if (l > 0)  v += U[(ch[l - 1] * 3 + 0) * 50 + o];
      if (l < 15) v += U[(ch[l + 1] * 3 + 2) * 50 + o];
      m = fmaxf(m, v);
    }
    dst[300 + o] = m;
  }
}

// ---------------- fp32 GEMM: C[16000][800] = A[16000][384] @ B[896][384]^T + bias
__global__ __launch_bounds__(256, 4) void gemm_kernel(
    const float* __restrict__ A, const float* __restrict__ B,
    float* __restrict__ C, const float* __restrict__ bf,
    const float* __restrict__ bb) {
  __shared__ float As[16][128];
  __shared__ float Bs[16][128];
  int tid = threadIdx.x;
  int m0 = blockIdx.x * 128;
  int n0 = blockIdx.y * 128;
  int tx = tid & 15, ty = tid >> 4;
  int lr = tid >> 2;
  int lc = (tid & 3) * 4;
  float acc[8][8];
#pragma unroll
  for (int i = 0; i < 8; i++)
#pragma unroll
    for (int j = 0; j < 8; j++) acc[i][j] = 0.f;

  for (int k0 = 0; k0 < 384; k0 += 16) {
#pragma unroll
    for (int h = 0; h < 2; h++) {
      int row = lr + h * 64;
      float4 av = *(const float4*)(A + (size_t)(m0 + row) * 384 + k0 + lc);
      As[lc + 0][row] = av.x; As[lc + 1][row] = av.y;
      As[lc + 2][row] = av.z; As[lc + 3][row] = av.w;
      float4 bv = *(const float4*)(B + (size_t)(n0 + row) * 384 + k0 + lc);
      Bs[lc + 0][row] = bv.x; Bs[lc + 1][row] = bv.y;
      Bs[lc + 2][row] = bv.z; Bs[lc + 3][row] = bv.w;
    }
    __syncthreads();
#pragma unroll
    for (int k = 0; k < 16; k++) {
      float a[8], b[8];
      *(float4*)&a[0] = *(const float4*)&As[k][ty * 8];
      *(float4*)&a[4] = *(const float4*)&As[k][ty * 8 + 4];
      *(float4*)&b[0] = *(const float4*)&Bs[k][tx * 8];
      *(float4*)&b[4] = *(const float4*)&Bs[k][tx * 8 + 4];
#pragma unroll
      for (int i = 0; i < 8; i++)
#pragma unroll
        for (int j = 0; j < 8; j++) acc[i][j] += a[i] * b[j];
    }
    __syncthreads();
  }
#pragma unroll
  for (int i = 0; i < 8; i++) {
    int m = m0 + ty * 8 + i;
#pragma unroll
    for (int jj = 0; jj < 8; jj++) {
      int j = n0 + tx * 8 + jj;
      if (j < 800) {
        float bias = (j < 400) ? bf[j] : bb[j - 400];
        C[(size_t)m * 800 + j] = acc[i][jj] + bias;
      }
    }
  }
}

// ---------------- BiLSTM scan: 128 blocks = (dir, row), 896 threads --------
// Wave-level K-split: waves 0-6 = K-half 0 (chunks 0-12, pre seed),
// waves 7-13 = K-half 1 (chunks 13-24). 52 weight floats/thread.
__global__ __launch_bounds__(896)
__attribute__((amdgpu_waves_per_eu(3, 4))) void lstm_kernel(
    const float* __restrict__ pre, const float* __restrict__ w_hh_f,
    const float* __restrict__ w_hh_b, const int* __restrict__ wordlen,
    float* __restrict__ lstm_out) {
  int t = threadIdx.x;
  int lane = t & 63;
  int w = t >> 6;                    // wave 0..13
  int grp = (w >= 7) ? 1 : 0;        // K-half (wave-uniform)
  int u = (w - grp * 7) * 64 + lane; // 0..447 within group
  int dir = blockIdx.x >> 6;
  int r = blockIdx.x & 63;
  int len = wordlen[r];
  const float* __restrict__ Wh = dir ? w_hh_b : w_hh_f;
  __shared__ __align__(16) float h0[112];
  __shared__ __align__(16) float h1[112];
  __shared__ float g_sh[400];

  const int v = u >> 2;              // hidden unit
  const int s = u & 3;               // gate: 0=i, 1=f, 2=g, 3=o
  const bool act = (v < 100);
  const int row = act ? (s * 100 + v) : 0;
  const bool g0act = (grp == 0) && act;

  // 13 NAMED float4 weight regs for this thread's K-half of its row.
  const float4* wrp = (const float4*)(Wh + (size_t)row * 100) + (grp ? 13 : 0);
  float4 W00 = wrp[0],  W01 = wrp[1],  W02 = wrp[2],  W03 = wrp[3];
  float4 W04 = wrp[4],  W05 = wrp[5],  W06 = wrp[6],  W07 = wrp[7];
  float4 W08 = wrp[8],  W09 = wrp[9],  W10 = wrp[10], W11 = wrp[11];
  float4 W12 = grp ? make_float4(0.f, 0.f, 0.f, 0.f) : wrp[12];

  // PIN: block remat of the weight loads (r5-r8 failure mode).
#define PIN4(W) asm volatile("" : "+v"(W.x), "+v"(W.y), "+v"(W.z), "+v"(W.w))
  PIN4(W00); PIN4(W01); PIN4(W02); PIN4(W03); PIN4(W04); PIN4(W05);
  PIN4(W06); PIN4(W07); PIN4(W08); PIN4(W09); PIN4(W10); PIN4(W11);
  PIN4(W12);
#undef PIN4

  if (t < 112) { h0[t] = 0.f; h1[t] = 0.f; }

  float c_reg = 0.f, h_reg = 0.f;
  const float* __restrict__ pr = pre + dir * 400;
  const int p0 = dir ? 249 : 0;
  const int dp = dir ? -1 : 1;
  const size_t rowbase = (size_t)r * 250;

  // depth-1 prefetch of this thread's pre column (group 0 only)
  float pv = 0.f;
  if (g0act) pv = pr[(rowbase + (size_t)p0) * 800 + row];
  const int cl = (lane < 25) ? lane : 0;  // h chunk owned by this lane
  __syncthreads();  // h buffers + weights ready

#define RL(x, q) __uint_as_float(__builtin_amdgcn_readlane(__float_as_uint(x), (q)))
#define DOTQ(q, Wq)                                                            \
  g += RL(hch.x, q) * Wq.x + RL(hch.y, q) * Wq.y + RL(hch.z, q) * Wq.z +       \
       RL(hch.w, q) * Wq.w;

#define LSTM_STEP(I, HRD, HWR)                                                 \
  do {                                                                         \
    const int p = p0 + dp * (I);                                               \
    const bool valid = (p < len); /* block-uniform */                          \
    float pvN = 0.f;                                                           \
    if (g0act) { /* issue next step's pre load BEFORE the dot */               \
      const int ip = ((I) + 1 < 250) ? (I) + 1 : (I);                          \
      pvN = pr[(rowbase + (size_t)(p0 + dp * ip)) * 800 + row];                \
    }                                                                          \
    float g = 0.f;                                                             \
    if (valid) {                                                               \
      float4 hch = *(const float4*)&(HRD)[4 * cl];                             \
      if (grp == 0) {                                                          \
        g = pv;                                                                \
        DOTQ(0, W00)  DOTQ(1, W01)  DOTQ(2, W02)  DOTQ(3, W03)                 \
        DOTQ(4, W04)  DOTQ(5, W05)  DOTQ(6, W06)  DOTQ(7, W07)                 \
        DOTQ(8, W08)  DOTQ(9, W09)  DOTQ(10, W10) DOTQ(11, W11)                \
        DOTQ(12, W12)                                                          \
      } else {                                                                 \
        DOTQ(13, W00) DOTQ(14, W01) DOTQ(15, W02) DOTQ(16, W03)                \
        DOTQ(17, W04) DOTQ(18, W05) DOTQ(19, W06) DOTQ(20, W07)                \
        DOTQ(21, W08) DOTQ(22, W09) DOTQ(23, W10) DOTQ(24, W11)                \
        if (act) g_sh[row] = g;                                                \
      }                                                                        \
    }                                                                          \
    pv = pvN;                                                                  \
    __syncthreads(); /* B1: g_sh(hi) visible; h reads of this step done */     \
    if (valid) {                                                               \
      if (grp == 0) {                                                          \
        const float gfull = g + g_sh[row];                                     \
        const float gf_in = __shfl_xor(gfull, 1, 64); /* f-gate */             \
        const float gg_in = __shfl_xor(gfull, 2, 64); /* g-gate */             \
        const float go_in = __shfl_xor(gfull, 3, 64); /* o-gate */             \
        if (act && s == 0) {                                                   \
          const float si = 1.f / (1.f + expf(-gfull));                         \
          const float sf = 1.f / (1.f + expf(-gf_in));                         \
          const float so = 1.f / (1.f + expf(-go_in));                         \
          c_reg = sf * c_reg + si * tanhf(gg_in);                              \
          h_reg = so * tanhf(c_reg);                                           \
          (HWR)[v] = h_reg;                                                    \
          lstm_out[(rowbase + (size_t)p) * 200 + dir * 100 + v] = h_reg;       \
        }                                                                      \
      }                                                                        \
    } else if (g0act && s == 0) {                                              \
      /* masked step: carry h; buffers untouched */                            \
      lstm_out[(rowbase + (size_t)p) * 200 + dir * 100 + v] = h_reg;           \
    }                                                                          \
    __syncthreads(); /* B2: h(HWR) visible; g_sh reads done */                 \
  } while (0)

#pragma unroll 1
  for (int ii = 0; ii < 250; ii += 2) {
    LSTM_STEP(ii,     h0, h1);
    LSTM_STEP(ii + 1, h1, h0);
  }
#undef LSTM_STEP
#undef DOTQ
#undef RL
}

// ---------------- projection: feats = lstm_out @ proj_w + proj_b ----------------
__global__ __launch_bounds__(256) void proj_kernel(
    const float* __restrict__ lstm_out, const float* __restrict__ proj_w,
    const float* __restrict__ proj_b, float* __restrict__ feats) {
  __shared__ float L[8][200];
  int tid = threadIdx.x;
  size_t base = (size_t)blockIdx.x * 8 * 200;
  for (int idx = tid; idx < 1600; idx += 256)
    L[idx / 200][idx % 200] = lstm_out[base + idx];
  __syncthreads();
  int ty = tid >> 5, c = tid & 31;
  if (c < 22) {
    float acc = proj_b[c];
#pragma unroll 8
    for (int k = 0; k < 200; k++) acc += L[ty][k] * proj_w[k * 22 + c];
    feats[((size_t)blockIdx.x * 8 + ty) * 22 + c] = acc;
  }
}

// ---------------- Viterbi: one wave per batch row (BORING: LDS delta) ----------
__global__ __launch_bounds__(64) void viterbi_kernel(
    const float* __restrict__ feats, const float* __restrict__ trans,
    const int* __restrict__ wordlen, int* __restrict__ out) {
  int r = blockIdx.x;
  int lane = threadIdx.x;
  __shared__ float dsh[22];          // delta (current)
  __shared__ float tsh[22][23];      // trans[k][c], padded stride 23
  __shared__ unsigned char bps[250][22];
  int len = wordlen[r];
  const float* __restrict__ fr = feats + (size_t)r * 250 * 22;
  for (int idx = lane; idx < 484; idx += 64)
    tsh[idx / 22][idx % 22] = trans[idx];
  if (lane < 22) dsh[lane] = trans[20 * 22 + lane] + fr[lane];  // START row
  __syncthreads();
  for (int t = 1; t < 250; t++) {
    float best = -1e30f, fv = 0.f;
    int arg = 0;
    if (lane < 22) {
      fv = fr[t * 22 + lane];
#pragma unroll
      for (int k = 0; k < 22; k++) {
        float cand = dsh[k] + tsh[k][lane];
        if (cand > best) { best = cand; arg = k; }  // first-max == np.argmax
      }
    }
    __syncthreads();  // all dsh reads complete
    if (lane < 22) {
      bool valid = t < len;
      if (valid) dsh[lane] = best + fv;
      bps[t][lane] = valid ? (unsigned char)arg : (unsigned char)lane;
    }
    __syncthreads();  // dsh writes visible
  }
  if (lane == 0) {
    float best = -1e30f;
    int last = 0;
#pragma unroll
    for (int k = 0; k < 22; k++) {
      float cand = dsh[k] + tsh[k][21];  // + trans[:, STOP]
      if (cand > best) { best = cand; last = k; }
    }
    int tag = last;
    out[r * 250 + 249] = tag;
    for (int t = 249; t >= 1; t--) {
      tag = bps[t][tag];
      out[r * 250 + t - 1] = tag;
    }
  }
}

extern "C" void kernel_launch(void* const* d_in, const int* in_sizes, int n_in,
                              void* d_out, int out_size, void* d_ws, size_t ws_size,
                              hipStream_t stream) {
  const int* batch_word  = (const int*)d_in[0];
  const int* batch_feats = (const int*)d_in[1];
  const int* wordlen     = (const int*)d_in[2];
  const int* batch_char  = (const int*)d_in[3];
  // d_in[4] batch_charlen: unused by reference
  const int* recover     = (const int*)d_in[5];
  // d_in[6] mask: recomputed from wordlen (bool dtype ambiguity)
  const float* char_emb  = (const float*)d_in[7];
  const float* word_emb  = (const float*)d_in[8];
  const float* feat_emb  = (const float*)d_in[9];
  const float* conv_w    = (const float*)d_in[10];
  const float* conv_b    = (const float*)d_in[11];
  const float* w_ih_f    = (const float*)d_in[12];
  const float* w_hh_f    = (const float*)d_in[13];
  const float* b_f       = (const float*)d_in[14];
  const float* w_ih_b    = (const float*)d_in[15];
  const float* w_hh_b    = (const float*)d_in[16];
  const float* b_b       = (const float*)d_in[17];
  const float* proj_w    = (const float*)d_in[18];
  const float* proj_b    = (const float*)d_in[19];
  const float* trans     = (const float*)d_in[20];
  int* out = (int*)d_out;
  float* ws = (float*)d_ws;

  float* U        = ws + WS_U;
  float* w_pad    = ws + WS_WPAD;
  float* wrep     = ws + WS_WREP;
  float* pre      = ws + WS_PRE;
  float* lstm_out = ws + WS_LSTM;   // aliases wrep (dead after gemm)
  float* feats    = ws + WS_FEATS;  // aliases wrep tail

  prepw_kernel<<<1344, 256, 0, stream>>>(w_ih_f, w_ih_b, w_pad);
  u_kernel<<<59, 256, 0, stream>>>(char_emb, conv_w, U);
  assemble_kernel<<<16000, 64, 0, stream>>>(batch_word, batch_feats, batch_char,
                                            recover, word_emb, feat_emb, conv_b,
                                            U, wrep);
  dim3 ggrid(125, 7);
  gemm_kernel<<<ggrid, 256, 0, stream>>>(wrep, w_pad, pre, b_f, b_b);
  lstm_kernel<<<128, 896, 0, stream>>>(pre, w_hh_f, w_hh_b, wordlen, lstm_out);
  proj_kernel<<<2000, 256, 0, stream>>>(lstm_out, proj_w, proj_b, feats);
  viterbi_kernel<<<64, 64, 0, stream>>>(feats, trans, wordlen, out);
}